// Round 7
// baseline (103.667 us; speedup 1.0000x reference)
//
#include <hip/hip_runtime.h>
#include <hip/hip_bf16.h>
#include <hip/hip_cooperative_groups.h>

namespace cg = cooperative_groups;

// EMD loss: input (N,C,S)=(32,256,4096) fp32, target (N,S) int32.
// out = mean_{n,s}[ sum_c (cumsum_c(input) - [c>=target])^2 / S ]
//
// R6 = R5 with compile fix: nt-loads need a NATIVE vector type, not
// HIP_vector_type. Use clang ext_vector_type(4) float.
//
// Structure (R5): single cooperative kernel, contiguous streaming.
//  - 256 blocks x 1024 threads = 1 block/CU, all co-resident.
//  - block (n,h) nt-streams rows [32h,32h+32) of slice n: 512KB perfectly
//    sequential per block (R3's structure, best per-byte so far).
//  - per-column chunk identity (proven exact in R2/R3):
//      sum_c (P+q-t)^2 = A + 2*P*B + CLEN*P^2,  P = prefix of chunk sums.
//    A,B stay in registers; only Q (4MB, L2/L3-absorbed) round-trips.
//  - grid.sync() x2 replaces phase2 + finisher dispatches; no memset/atomics.

#define N_DIM 32
#define C_DIM 256
#define S_DIM 4096
#define H_SPLIT 8
#define CLEN (C_DIM / H_SPLIT)      // 32
#define S4 (S_DIM / 4)              // 1024 float4 per row
#define NBLK (N_DIM * H_SPLIT)      // 256
// /S (per-column norm) * /(N*S) (mean) = 1/2^29, exact in fp32
#define SCALE (1.0f / (float)(1u << 29))

typedef float f32x4 __attribute__((ext_vector_type(4)));
typedef int   i32x4 __attribute__((ext_vector_type(4)));

__global__ __launch_bounds__(1024) void emd_coop(
    const f32x4* __restrict__ in4, const i32x4* __restrict__ tgt4,
    f32x4* __restrict__ wsQ,       // [H_SPLIT*N_DIM][S4] f32x4
    float* __restrict__ partials,  // [NBLK]
    float* __restrict__ out)
{
    const int tid = threadIdx.x;                // float4 slot within row
    const int n   = blockIdx.x >> 3;
    const int h   = blockIdx.x & 7;

    const f32x4* p = in4 + ((size_t)(n * C_DIM + h * CLEN)) * S4 + tid;

    const i32x4 T = tgt4[n * S4 + tid];
    const int Tx = T.x - h * CLEN;
    const int Ty = T.y - h * CLEN;
    const int Tz = T.z - h * CLEN;
    const int Tw = T.w - h * CLEN;

    f32x4 q = (f32x4)(0.f);     // chunk-local cumsum
    f32x4 A = (f32x4)(0.f);     // sum (q-t)^2
    f32x4 B = (f32x4)(0.f);     // sum (q-t)

    #pragma unroll 8
    for (int c = 0; c < CLEN; ++c) {
        const f32x4 v = __builtin_nontemporal_load(p + (size_t)c * S4);
        q += v;
        const float d0 = q.x - ((c >= Tx) ? 1.0f : 0.0f);
        const float d1 = q.y - ((c >= Ty) ? 1.0f : 0.0f);
        const float d2 = q.z - ((c >= Tz) ? 1.0f : 0.0f);
        const float d3 = q.w - ((c >= Tw) ? 1.0f : 0.0f);
        A.x = fmaf(d0, d0, A.x);  B.x += d0;
        A.y = fmaf(d1, d1, A.y);  B.y += d1;
        A.z = fmaf(d2, d2, A.z);  B.z += d2;
        A.w = fmaf(d3, d3, A.w);  B.w += d3;
    }

    // publish chunk sums (4MB total; L2/L3 absorbed)
    wsQ[(h * N_DIM + n) * S4 + tid] = q;

    cg::this_grid().sync();

    // exclusive prefix over chunks g<h for this column (block-uniform count)
    f32x4 P = (f32x4)(0.f);
    #pragma unroll
    for (int g = 0; g < H_SPLIT - 1; ++g) {
        if (g < h) {
            const f32x4 Qg = wsQ[(g * N_DIM + n) * S4 + tid];
            P += Qg;
        }
    }

    float val = (A.x + A.y + A.z + A.w)
              + 2.0f * (P.x * B.x + P.y * B.y + P.z * B.z + P.w * B.w)
              + (float)CLEN * (P.x * P.x + P.y * P.y + P.z * P.z + P.w * P.w);
    float a = val * SCALE;

    // wave reduce, then block reduce to one partial per block
    #pragma unroll
    for (int off = 32; off > 0; off >>= 1)
        a += __shfl_down(a, off, 64);

    __shared__ float wpart[16];
    const int lane = tid & 63, wid = tid >> 6;
    if (lane == 0) wpart[wid] = a;
    __syncthreads();
    if (tid == 0) {
        float s = 0.f;
        #pragma unroll
        for (int w = 0; w < 16; ++w) s += wpart[w];
        partials[blockIdx.x] = s;
    }

    cg::this_grid().sync();

    // block 0, one wave: deterministic final sum of 256 partials
    if (blockIdx.x == 0 && tid < 64) {
        float s = 0.f;
        #pragma unroll
        for (int k = 0; k < NBLK / 64; ++k)
            s += partials[tid + 64 * k];
        #pragma unroll
        for (int off = 32; off > 0; off >>= 1)
            s += __shfl_down(s, off, 64);
        if (tid == 0) out[0] = s;
    }
}

extern "C" void kernel_launch(void* const* d_in, const int* in_sizes, int n_in,
                              void* d_out, int out_size, void* d_ws, size_t ws_size,
                              hipStream_t stream) {
    const f32x4* in4  = (const f32x4*)d_in[0];
    const i32x4* tgt4 = (const i32x4*)d_in[1];
    float*       out  = (float*)d_out;

    f32x4* wsQ      = (f32x4*)d_ws;                               // 4 MB
    float* partials = (float*)d_ws + (size_t)H_SPLIT * N_DIM * S_DIM; // after Q

    void* args[] = { (void*)&in4, (void*)&tgt4, (void*)&wsQ,
                     (void*)&partials, (void*)&out };
    (void)hipLaunchCooperativeKernel((const void*)emd_coop,
                                     dim3(NBLK), dim3(1024),
                                     args, 0, stream);
}

// Round 8
// 34.339 us; speedup vs baseline: 3.0190x; 3.0190x over previous
//
#include <hip/hip_runtime.h>
#include <hip/hip_bf16.h>

// EMD loss: input (N,C,S)=(32,256,4096) fp32, target (N,S) int32.
// out = mean_{n,s}[ sum_c (cumsum_c(input) - [c>=target])^2 / S ]
//
// R7 = R4 with ONE change: drop __builtin_nontemporal_load.
// Rationale: R6's rocprof showed FETCH_SIZE=74.8MB per run -> 45% of the
// 134MB input was L3-resident across runs DESPITE nt hints. Input (134MB)
// fits in L3 (256MB); nt marks lines early-evict and likely caps the hit
// rate. Plain loads should let the whole input stay L3-warm across graph
// replays -> read at Infinity-Cache BW instead of the ~4.5 TB/s plateau.
// Everything else identical to R4 (34.0 us): 1 thread/column, 512 blk x 256,
// unroll 32, block partials -> 1-wave finisher (no memset, no atomics).

#define N_DIM 32
#define C_DIM 256
#define S_DIM 4096
#define S_SHIFT 12
#define S_MASK  (S_DIM - 1)
#define NBLOCKS ((N_DIM * S_DIM) / 256)   // 512
// /S (per-column norm) * /(N*S) (mean) = 1/2^29, exact in fp32
#define SCALE (1.0f / (float)(1u << 29))

__global__ __launch_bounds__(256) void emd_main(
    const float* __restrict__ in, const int* __restrict__ tgt,
    float* __restrict__ partials)
{
    const int j = blockIdx.x * 256 + threadIdx.x;   // column id in [0, N*S)
    const int n = j >> S_SHIFT;
    const int s = j & S_MASK;
    const int T = tgt[j];

    const float* p = in + (size_t)n * (C_DIM * (size_t)S_DIM) + s;

    float cum = 0.0f;
    float acc = 0.0f;
    #pragma unroll 32
    for (int c = 0; c < C_DIM; ++c) {
        const float v = p[(size_t)c * S_DIM];
        cum += v;
        const float d = cum - ((c >= T) ? 1.0f : 0.0f);
        acc = fmaf(d, d, acc);
    }

    float a = acc * SCALE;

    // wave (64-lane) shuffle reduction
    #pragma unroll
    for (int off = 32; off > 0; off >>= 1)
        a += __shfl_down(a, off, 64);

    __shared__ float ws[4];
    const int lane = threadIdx.x & 63;
    const int wid  = threadIdx.x >> 6;
    if (lane == 0) ws[wid] = a;
    __syncthreads();
    if (threadIdx.x == 0)
        partials[blockIdx.x] = ws[0] + ws[1] + ws[2] + ws[3];
}

__global__ __launch_bounds__(64) void emd_finish(
    const float* __restrict__ partials, float* __restrict__ out)
{
    const int lane = threadIdx.x;
    float a = 0.0f;
    #pragma unroll
    for (int k = 0; k < NBLOCKS / 64; ++k)     // 8 per lane, fixed order
        a += partials[lane + 64 * k];
    #pragma unroll
    for (int off = 32; off > 0; off >>= 1)
        a += __shfl_down(a, off, 64);
    if (lane == 0)
        out[0] = a;
}

extern "C" void kernel_launch(void* const* d_in, const int* in_sizes, int n_in,
                              void* d_out, int out_size, void* d_ws, size_t ws_size,
                              hipStream_t stream) {
    const float* in  = (const float*)d_in[0];
    const int*   tgt = (const int*)d_in[1];
    float*       out = (float*)d_out;
    float*       partials = (float*)d_ws;    // 512 floats, overwritten each call

    emd_main<<<NBLOCKS, 256, 0, stream>>>(in, tgt, partials);
    emd_finish<<<1, 64, 0, stream>>>(partials, out);
}

// Round 9
// 26.702 us; speedup vs baseline: 3.8824x; 1.2860x over previous
//
#include <hip/hip_runtime.h>
#include <hip/hip_bf16.h>

// EMD loss: input (N,C,S)=(32,256,4096) fp32, target (N,S) int32.
// out = mean_{n,s}[ sum_c (cumsum_c(input) - [c>=target])^2 / S ]
//
// R8: the untested cell of the {request width x occupancy} matrix:
// float4 (16B/lane, 1KB/wave per request -- fill-like) AND 8 waves/CU.
//   thread (j4, h): float4-column j4 (32768 of them), C-chunk h of 64 rows.
//   131072 threads = 512 blocks x 256 = 2048 waves = 8 waves/CU.
//   Per wave: 64 lanes x 16B = 1KB contiguous per c-step; unroll 8.
// Cross-chunk coupling by the exact identity (verified R2/R3, absmax 0.0):
//   sum_c (P+q-t)^2 = A + 2 P B + CLEN P^2, P = prefix of chunk sums,
//   exchanged via LDS within the block (chunks of a column share a block).

#define N_DIM 32
#define C_DIM 256
#define S_DIM 4096
#define H_SPLIT 4
#define CLEN (C_DIM / H_SPLIT)     // 64
#define S4 (S_DIM / 4)             // 1024 float4 per row
#define NBLOCKS 512
// /S (per-column norm) * /(N*S) (mean) = 1/2^29, exact in fp32
#define SCALE (1.0f / (float)(1u << 29))

typedef float f32x4 __attribute__((ext_vector_type(4)));

__global__ __launch_bounds__(256) void emd_main(
    const f32x4* __restrict__ in4, const int* __restrict__ tgt,
    float* __restrict__ partials)
{
    const int tid  = threadIdx.x;
    const int lane = tid & 63;                 // j4 offset within block
    const int h    = tid >> 6;                 // chunk id = wave id
    const int j4   = blockIdx.x * 64 + lane;   // float4-column in [0, 32768)
    const int n    = j4 >> 10;                 // j4 / S4
    const int s4   = j4 & (S4 - 1);

    const f32x4* p = in4 + ((size_t)(n * C_DIM + h * CLEN)) * S4 + s4;

    const int4 T = reinterpret_cast<const int4*>(tgt)[j4];
    const int Tx = T.x - h * CLEN;
    const int Ty = T.y - h * CLEN;
    const int Tz = T.z - h * CLEN;
    const int Tw = T.w - h * CLEN;

    f32x4 q = (f32x4)(0.f);    // chunk-local cumsum
    f32x4 A = (f32x4)(0.f);    // sum (q-t)^2
    f32x4 B = (f32x4)(0.f);    // sum (q-t)

    #pragma unroll 8
    for (int c = 0; c < CLEN; ++c) {
        const f32x4 v = p[(size_t)c * S4];
        q += v;
        const float d0 = q.x - ((c >= Tx) ? 1.0f : 0.0f);
        const float d1 = q.y - ((c >= Ty) ? 1.0f : 0.0f);
        const float d2 = q.z - ((c >= Tz) ? 1.0f : 0.0f);
        const float d3 = q.w - ((c >= Tw) ? 1.0f : 0.0f);
        A.x = fmaf(d0, d0, A.x);  B.x += d0;
        A.y = fmaf(d1, d1, A.y);  B.y += d1;
        A.z = fmaf(d2, d2, A.z);  B.z += d2;
        A.w = fmaf(d3, d3, A.w);  B.w += d3;
    }

    // exchange chunk sums within the block; P = exclusive prefix over chunks
    __shared__ f32x4 csum[H_SPLIT][64];
    csum[h][lane] = q;
    __syncthreads();

    f32x4 P = (f32x4)(0.f);
    #pragma unroll
    for (int g = 0; g < H_SPLIT - 1; ++g)
        if (g < h) P += csum[g][lane];

    float val = (A.x + A.y + A.z + A.w)
              + 2.0f * (P.x * B.x + P.y * B.y + P.z * B.z + P.w * B.w)
              + (float)CLEN * (P.x * P.x + P.y * P.y + P.z * P.z + P.w * P.w);
    float a = val * SCALE;

    // wave reduce -> per-wave partial -> block partial
    #pragma unroll
    for (int off = 32; off > 0; off >>= 1)
        a += __shfl_down(a, off, 64);

    __shared__ float wpart[H_SPLIT];
    if (lane == 0) wpart[h] = a;
    __syncthreads();
    if (tid == 0)
        partials[blockIdx.x] = wpart[0] + wpart[1] + wpart[2] + wpart[3];
}

__global__ __launch_bounds__(64) void emd_finish(
    const float* __restrict__ partials, float* __restrict__ out)
{
    const int lane = threadIdx.x;
    float a = 0.0f;
    #pragma unroll
    for (int k = 0; k < NBLOCKS / 64; ++k)     // 8 per lane, fixed order
        a += partials[lane + 64 * k];
    #pragma unroll
    for (int off = 32; off > 0; off >>= 1)
        a += __shfl_down(a, off, 64);
    if (lane == 0)
        out[0] = a;
}

extern "C" void kernel_launch(void* const* d_in, const int* in_sizes, int n_in,
                              void* d_out, int out_size, void* d_ws, size_t ws_size,
                              hipStream_t stream) {
    const f32x4* in4 = (const f32x4*)d_in[0];
    const int*   tgt = (const int*)d_in[1];
    float*       out = (float*)d_out;
    float*       partials = (float*)d_ws;    // 512 floats, overwritten each call

    emd_main<<<NBLOCKS, 256, 0, stream>>>(in4, tgt, partials);
    emd_finish<<<1, 64, 0, stream>>>(partials, out);
}